// Round 1
// baseline (241.593 us; speedup 1.0000x reference)
//
#include <hip/hip_runtime.h>

typedef __bf16 bf16x8 __attribute__((ext_vector_type(8)));
typedef float  f32x4  __attribute__((ext_vector_type(4)));

__device__ __forceinline__ unsigned short f2bf(float f) {
  unsigned int u = __builtin_bit_cast(unsigned int, f);
  u = u + 0x7fffu + ((u >> 16) & 1u);
  return (unsigned short)(u >> 16);
}

// ws layout (ushort elements):
//   W1b [256][256] @ 0        (row-major, N x K)
//   W2b [256][256] @ 65536
//   W3b [256][640] @ 131072
//   W4b [16][256]  @ 294912   (rows 8..15 zeroed)
#define O_W2 65536
#define O_W3 131072
#define O_W4 294912
#define N_PREP 299008

__global__ void prep_kernel(const float* __restrict__ W1, const float* __restrict__ W2,
                            const float* __restrict__ W3, const float* __restrict__ W4,
                            unsigned short* __restrict__ ws) {
  int id = blockIdx.x * 256 + threadIdx.x;
  if (id < O_W2) {
    ws[id] = f2bf(W1[id]);
  } else if (id < O_W3) {
    ws[id] = f2bf(W2[id - O_W2]);
  } else if (id < O_W4) {
    ws[id] = f2bf(W3[id - O_W3]);
  } else if (id < N_PREP) {
    int t = id - O_W4;
    ws[id] = (t < 2048) ? f2bf(W4[t]) : (unsigned short)0;
  }
}

#define XSTR 648   // xxx row stride (elems): 1296B = 16B-aligned, rotates 4 banks/row
#define YSTR 264   // ytl row stride (elems): 528B  = 16B-aligned, rotates 4 banks/row

__global__ __launch_bounds__(512, 2) void actor_kernel(
    const float* __restrict__ state,
    const float* __restrict__ b1, const float* __restrict__ b2,
    const float* __restrict__ b3, const float* __restrict__ b4,
    const unsigned short* __restrict__ wsb,
    float* __restrict__ out)
{
  // xxx row r: cols [0,256)   = h_i (bf16, written after GEMM1 combine)
  //            cols [256,640) = s[r][0] | s[r][1] | s[r][2]  (bf16 state)
  __shared__ unsigned short xxx[64 * XSTR];   // 82944 B
  __shared__ unsigned short ytl[64 * YSTR];   // 33792 B

  const int tid  = threadIdx.x;
  const int w    = tid >> 6;     // wave 0..7
  const int lane = tid & 63;
  const int lr   = lane & 15;    // row-in-tile (A/B) / col (D)
  const int lg   = lane >> 4;    // k-group 0..3
  const long b0  = (long)blockIdx.x * 64;

  // ---- Phase 0: stage 64 state rows (64x384 f32) into xxx cols 256..639 as bf16 ----
  {
    const float4* sp = (const float4*)(state + b0 * 384);
    #pragma unroll
    for (int t = 0; t < 12; ++t) {
      int f = tid + t * 512;             // float4 index, < 6144
      float4 v = sp[f];
      int r   = f / 96;
      int rem = f - r * 96;
      int i   = rem >> 5;
      int k4  = (rem & 31) << 2;
      ushort4 u;
      u.x = f2bf(v.x); u.y = f2bf(v.y); u.z = f2bf(v.z); u.w = f2bf(v.w);
      *(ushort4*)&xxx[r * XSTR + 256 + i * 128 + k4] = u;
    }
  }
  __syncthreads();

  const int n0 = w * 32;   // this wave's 32-col slice of every N dimension

  // ---- GEMM1: agents(128x256) @ {W1,W2}^T, + bias, relu, 2-way softmax combine ----
  // agents row m = 2r+p: k<128 -> s0[r] (xxx col 256+k), k>=128 -> s[1+p][r] (xxx col 384+p*128+k-128)
  #pragma unroll
  for (int sc = 0; sc < 2; ++sc) {
    const int ncol = n0 + sc * 16 + lr;        // output column this lane owns
    f32x4 accH[8], accE[8];
    #pragma unroll
    for (int rt = 0; rt < 8; ++rt) {
      accH[rt] = (f32x4){0.f, 0.f, 0.f, 0.f};
      accE[rt] = (f32x4){0.f, 0.f, 0.f, 0.f};
    }
    const unsigned short* w1p = wsb + ncol * 256 + lg * 8;
    const unsigned short* w2p = wsb + O_W2 + ncol * 256 + lg * 8;

    bf16x8 bh = *(const bf16x8*)(w1p);
    bf16x8 be = *(const bf16x8*)(w2p);
    #pragma unroll
    for (int ks = 0; ks < 8; ++ks) {
      bf16x8 bhn, ben;
      if (ks < 7) {
        bhn = *(const bf16x8*)(w1p + (ks + 1) * 32);
        ben = *(const bf16x8*)(w2p + (ks + 1) * 32);
      }
      const int colo = (ks < 4) ? (256 + ks * 32 + lg * 8)
                                : (384 + (ks - 4) * 32 + lg * 8);
      #pragma unroll
      for (int rt = 0; rt < 8; ++rt) {
        const int m = rt * 16 + lr;
        const int addr = (m >> 1) * XSTR + colo + ((ks >= 4) ? ((m & 1) << 7) : 0);
        bf16x8 a = *(const bf16x8*)&xxx[addr];
        accH[rt] = __builtin_amdgcn_mfma_f32_16x16x32_bf16(a, bh, accH[rt], 0, 0, 0);
        accE[rt] = __builtin_amdgcn_mfma_f32_16x16x32_bf16(a, be, accE[rt], 0, 0, 0);
      }
      bh = bhn; be = ben;
    }

    // combine: D-frag rows (lg*4+reg); pairs (reg0,reg1)->r0, (reg2,reg3)->r0+1
    const float b1v = b1[ncol];
    const float b2v = b2[ncol];
    #pragma unroll
    for (int rt = 0; rt < 8; ++rt) {
      const int r0 = rt * 8 + lg * 2;
      #pragma unroll
      for (int pr = 0; pr < 2; ++pr) {
        float h0 = fmaxf(accH[rt][2 * pr + 0] + b1v, 0.f);
        float h1 = fmaxf(accH[rt][2 * pr + 1] + b1v, 0.f);
        float e0 = fmaxf(accE[rt][2 * pr + 0] + b2v, 0.f);
        float e1 = fmaxf(accE[rt][2 * pr + 1] + b2v, 0.f);
        float a0 = 1.0f / (1.0f + __expf(e1 - e0));   // softmax weight of agent 0
        float hi = h1 + a0 * (h0 - h1);
        xxx[(r0 + pr) * XSTR + ncol] = f2bf(hi);
      }
    }
  }
  __syncthreads();

  // ---- GEMM3: xxx(64x640) @ W3^T, + b3, relu -> ytl bf16 ----
  {
    f32x4 acc3[4][2];
    #pragma unroll
    for (int rt = 0; rt < 4; ++rt) {
      acc3[rt][0] = (f32x4){0.f, 0.f, 0.f, 0.f};
      acc3[rt][1] = (f32x4){0.f, 0.f, 0.f, 0.f};
    }
    const unsigned short* w3pa = wsb + O_W3 + (n0 + lr) * 640 + lg * 8;
    const unsigned short* w3pb = wsb + O_W3 + (n0 + 16 + lr) * 640 + lg * 8;
    bf16x8 ba = *(const bf16x8*)(w3pa);
    bf16x8 bb = *(const bf16x8*)(w3pb);
    for (int ks = 0; ks < 20; ++ks) {
      bf16x8 ban, bbn;
      if (ks < 19) {
        ban = *(const bf16x8*)(w3pa + (ks + 1) * 32);
        bbn = *(const bf16x8*)(w3pb + (ks + 1) * 32);
      }
      #pragma unroll
      for (int rt = 0; rt < 4; ++rt) {
        bf16x8 a = *(const bf16x8*)&xxx[(rt * 16 + lr) * XSTR + ks * 32 + lg * 8];
        acc3[rt][0] = __builtin_amdgcn_mfma_f32_16x16x32_bf16(a, ba, acc3[rt][0], 0, 0, 0);
        acc3[rt][1] = __builtin_amdgcn_mfma_f32_16x16x32_bf16(a, bb, acc3[rt][1], 0, 0, 0);
      }
      ba = ban; bb = bbn;
    }
    const float b3a = b3[n0 + lr];
    const float b3b = b3[n0 + 16 + lr];
    #pragma unroll
    for (int rt = 0; rt < 4; ++rt) {
      #pragma unroll
      for (int reg = 0; reg < 4; ++reg) {
        int row = rt * 16 + lg * 4 + reg;
        float va = fmaxf(acc3[rt][0][reg] + b3a, 0.f);
        float vb = fmaxf(acc3[rt][1][reg] + b3b, 0.f);
        ytl[row * YSTR + n0 + lr]      = f2bf(va);
        ytl[row * YSTR + n0 + 16 + lr] = f2bf(vb);
      }
    }
  }
  __syncthreads();

  // ---- GEMM4: ytl(64x256) @ W4b^T (16 rows, 8 valid), + b4, tanh -> out ----
  if (w < 4) {
    f32x4 acc4 = (f32x4){0.f, 0.f, 0.f, 0.f};
    const unsigned short* w4p = wsb + O_W4 + lr * 256 + lg * 8;
    #pragma unroll
    for (int ks = 0; ks < 8; ++ks) {
      bf16x8 a = *(const bf16x8*)&ytl[(w * 16 + lr) * YSTR + ks * 32 + lg * 8];
      bf16x8 b = *(const bf16x8*)(w4p + ks * 32);
      acc4 = __builtin_amdgcn_mfma_f32_16x16x32_bf16(a, b, acc4, 0, 0, 0);
    }
    if (lr < 8) {
      const float b4v = b4[lr];
      #pragma unroll
      for (int reg = 0; reg < 4; ++reg) {
        long row = b0 + w * 16 + lg * 4 + reg;
        out[row * 8 + lr] = tanhf(acc4[reg] + b4v);
      }
    }
  }
}

extern "C" void kernel_launch(void* const* d_in, const int* in_sizes, int n_in,
                              void* d_out, int out_size, void* d_ws, size_t ws_size,
                              hipStream_t stream) {
  const float* state = (const float*)d_in[0];
  const float* W1 = (const float*)d_in[1];
  const float* b1 = (const float*)d_in[2];
  const float* W2 = (const float*)d_in[3];
  const float* b2 = (const float*)d_in[4];
  const float* W3 = (const float*)d_in[5];
  const float* b3 = (const float*)d_in[6];
  const float* W4 = (const float*)d_in[7];
  const float* b4 = (const float*)d_in[8];

  unsigned short* wsb = (unsigned short*)d_ws;

  prep_kernel<<<(N_PREP + 255) / 256, 256, 0, stream>>>(W1, W2, W3, W4, wsb);
  actor_kernel<<<1024, 512, 0, stream>>>(state, b1, b2, b3, b4, wsb, (float*)d_out);
}